// Round 11
// baseline (1940.962 us; speedup 1.0000x reference)
//
#include <hip/hip_runtime.h>
#include <math.h>

typedef unsigned short u16;
typedef unsigned int u32;
typedef __attribute__((ext_vector_type(8))) __bf16 bf16x8;
typedef __attribute__((ext_vector_type(4))) float f32x4;
typedef __attribute__((ext_vector_type(8))) unsigned short ushort8v;
typedef __attribute__((ext_vector_type(4))) float float4v;
typedef __attribute__((ext_vector_type(4))) unsigned short u16x4;

typedef const __attribute__((address_space(1))) void gvoid_t;
typedef __attribute__((address_space(3))) void lvoid_t;

#define MFMA(a, b, c) __builtin_amdgcn_mfma_f32_16x16x32_bf16((a), (b), (c), 0, 0, 0)

// native RNE f32->bf16
__device__ __forceinline__ u16 f2bf(float f) {
  __bf16 h = (__bf16)f;
  return __builtin_bit_cast(u16, h);
}

// ---------------------------------------------------------------------------
// [rows][64] bf16 tiles (128B rows), XOR-swizzled source + swizzled reads
// (involution (r&7)<<4) -> conflict-free ds_read_b128. (proven 0-conflict)
// ---------------------------------------------------------------------------
__device__ __forceinline__ void stage64(const u16* g, int ldg, u16* lds, int rows, int tid) {
  int w = tid >> 6, l = tid & 63;
  int lr = l >> 3;
  int cb = (l & 7) << 4;
  for (int it = 0; it < rows; it += 32) {
    int rbase = it + w * 8;
    int r = rbase + lr;
    int scb = cb ^ ((r & 7) << 4);
    const char* gp = (const char*)(g + (size_t)r * ldg) + scb;
    char* lp = (char*)lds + (size_t)rbase * 128;
    __builtin_amdgcn_global_load_lds((gvoid_t*)gp, (lvoid_t*)lp, 16, 0, 0);
  }
}

__device__ __forceinline__ bf16x8 ldsfrag(const u16* base, int row, int e0) {
  int boff = row * 128 + (((e0) << 1) ^ ((row & 7) << 4));
  return *(const bf16x8*)((const char*)base + boff);
}

// ---------------------------------------------------------------------------
// embed
// ---------------------------------------------------------------------------
__global__ void embed_kernel(const int* __restrict__ tok, const float* __restrict__ emb,
                             const float* __restrict__ pe, float* __restrict__ xf) {
  int row = blockIdx.x;
  int tid = threadIdx.x;              // 192
  int t = tok[row];
  int spos = row & 1023;
  float4v e = ((const float4v*)(emb + (size_t)t * 768))[tid];
  float4v p = ((const float4v*)(pe + (size_t)spos * 768))[tid];
  float4v r;
  r.x = e.x + p.x; r.y = e.y + p.y; r.z = e.z + p.z; r.w = e.w + p.w;
  ((float4v*)(xf + (size_t)row * 768))[tid] = r;
}

// ---------------------------------------------------------------------------
// layernorm: one WAVE per row (4 rows / 256-thr block), pure shuffle
// reduction — no LDS, no __syncthreads. (r10 proven win)
// ---------------------------------------------------------------------------
__global__ __launch_bounds__(256) void ln_kernel(const float* __restrict__ x,
                                                 const float* __restrict__ sc,
                                                 const float* __restrict__ bi,
                                                 u16* __restrict__ out) {
  int w = threadIdx.x >> 6, lane = threadIdx.x & 63;
  int row = blockIdx.x * 4 + w;
  const float* xr = x + (size_t)row * 768;
  float4v v[3];
  #pragma unroll
  for (int c = 0; c < 3; ++c) v[c] = ((const float4v*)xr)[c * 64 + lane];
  float s = 0.0f, s2 = 0.0f;
  #pragma unroll
  for (int c = 0; c < 3; ++c) {
    s += v[c].x + v[c].y + v[c].z + v[c].w;
    s2 += v[c].x * v[c].x + v[c].y * v[c].y + v[c].z * v[c].z + v[c].w * v[c].w;
  }
  #pragma unroll
  for (int off = 32; off >= 1; off >>= 1) {
    s += __shfl_down(s, off);
    s2 += __shfl_down(s2, off);
  }
  s = __shfl(s, 0);
  s2 = __shfl(s2, 0);
  float m = s * (1.0f / 768.0f);
  float var = s2 * (1.0f / 768.0f) - m * m;
  float rs = rsqrtf(var + 1e-5f);
  u16* or_ = out + (size_t)row * 768;
  #pragma unroll
  for (int c = 0; c < 3; ++c) {
    float4v sv = ((const float4v*)sc)[c * 64 + lane];
    float4v bv = ((const float4v*)bi)[c * 64 + lane];
    u16x4 ov;
    ov.x = f2bf((v[c].x - m) * rs * sv.x + bv.x);
    ov.y = f2bf((v[c].y - m) * rs * sv.y + bv.y);
    ov.z = f2bf((v[c].z - m) * rs * sv.z + bv.z);
    ov.w = f2bf((v[c].w - m) * rs * sv.w + bv.w);
    ((u16x4*)or_)[c * 64 + lane] = ov;
  }
}

// ---------------------------------------------------------------------------
// weight converters: f32 [K][N] -> bf16 [N][K]
// ---------------------------------------------------------------------------
__global__ void convT_kernel(const float* __restrict__ src, u16* __restrict__ dst,
                             int N, int K, long long sz, long long dz) {
  src += (size_t)blockIdx.z * sz;
  dst += (size_t)blockIdx.z * dz;
  __shared__ float t[32][33];
  int n0 = blockIdx.x * 32, k0 = blockIdx.y * 32;
  int tid = threadIdx.x;
  int tx = tid & 31, ty = tid >> 5;
  for (int r = ty; r < 32; r += 8) t[r][tx] = src[(size_t)(k0 + r) * N + n0 + tx];
  __syncthreads();
  for (int r = ty; r < 32; r += 8) dst[(size_t)(n0 + r) * K + k0 + tx] = f2bf(t[tx][r]);
}

__global__ void convqkvT_kernel(const float* __restrict__ wq, const float* __restrict__ wk,
                                const float* __restrict__ wv, u16* __restrict__ dst,
                                long long wz, long long dz) {
  __shared__ float t[32][33];
  int n0 = blockIdx.x * 32, k0 = blockIdx.y * 32;
  int which = n0 / 768;
  int r0 = n0 % 768;
  int h = r0 >> 6, e0 = r0 & 63;
  const float* src = which == 0 ? wq : (which == 1 ? wk : wv);
  src += (size_t)blockIdx.z * wz;
  dst += (size_t)blockIdx.z * dz;
  int tid = threadIdx.x;
  int tx = tid & 31, ty = tid >> 5;
  for (int r = ty; r < 32; r += 8) t[r][tx] = src[(size_t)(h * 768 + k0 + r) * 64 + e0 + tx];
  __syncthreads();
  for (int r = ty; r < 32; r += 8) dst[(size_t)(n0 + r) * 768 + k0 + tx] = f2bf(t[tx][r]);
}

// ---------------------------------------------------------------------------
// v [bh][s][e] -> vt [bh][e][s]  (round-6 proven)
// ---------------------------------------------------------------------------
__global__ void transpose_v_kernel(const u16* __restrict__ v, u16* __restrict__ vt) {
  __shared__ u16 t[64][72];
  int bh = blockIdx.x, sc = blockIdx.y;
  int tid = threadIdx.x;
  const u16* src = v + ((size_t)bh * 1024 + sc * 64) * 64;
  int sl = tid >> 2, e0 = (tid & 3) * 16;
  ushort8v a = *(const ushort8v*)(src + (size_t)sl * 64 + e0);
  ushort8v b = *(const ushort8v*)(src + (size_t)sl * 64 + e0 + 8);
  #pragma unroll
  for (int j = 0; j < 8; ++j) t[sl][e0 + j] = a[j];
  #pragma unroll
  for (int j = 0; j < 8; ++j) t[sl][e0 + 8 + j] = b[j];
  __syncthreads();
  int e = tid >> 2, s0 = (tid & 3) * 16;
  ushort8v o0, o1;
  #pragma unroll
  for (int j = 0; j < 8; ++j) o0[j] = t[s0 + j][e];
  #pragma unroll
  for (int j = 0; j < 8; ++j) o1[j] = t[s0 + 8 + j][e];
  u16* dst = vt + ((size_t)bh * 64 + e) * 1024 + sc * 64 + s0;
  *(ushort8v*)dst = o0;
  *(ushort8v*)(dst + 8) = o1;
}

// ---------------------------------------------------------------------------
// gemm128 (round-6 proven loop + T1 XCD swizzle): C[M,N] = A[M,K]*Wt[N,K],
// 128xBN tile, BK=64, 4 waves, 2-barrier loop, global_load_lds width-16,
// both-sides XOR swizzle, hoisted addresses, NK=6 unroll x kOuter chunks
// (r6-proven fastest). XCD swizzle: HW dispatches linear id L x-fastest,
// round-robin L%8 across XCDs; remap so each XCD owns a CONTIGUOUS chunk of
// logical tiles -> its L2 holds few B-strips (nwg%8==0 for all our grids).
// MODE 0: QKV scatter  MODE 1: xf += C  MODE 2: gelu(C+b1)->bf16
// MODE 3: xf += C + b2 (+ optional outf f32 copy)
// ---------------------------------------------------------------------------
template <int MODE, int NK, int BN>
__global__ __launch_bounds__(256) void gemm128(
    const u16* __restrict__ A, int lda, const u16* __restrict__ Wt, int ldb, int kOuter,
    float* __restrict__ xf, u16* __restrict__ outb, const float* __restrict__ bias,
    u16* __restrict__ qb, u16* __restrict__ kb, u16* __restrict__ vb,
    float* __restrict__ outf) {
  constexpr int NT = BN / 32;                 // B frags per wave (4 or 2)
  constexpr int NBAND = BN / 2;               // wave N width
  __shared__ alignas(16) u16 As[128 * 64];
  __shared__ alignas(16) u16 Bs[BN * 64];
  int tid = threadIdx.x, lane = tid & 63, w = tid >> 6;
  int wm = w >> 1, wn = w & 1;
  // XCD-aware bijective swizzle (nwg % 8 == 0 guaranteed by launch)
  int gx = gridDim.x;
  int L = blockIdx.y * gx + blockIdx.x;
  int qc = (gx * gridDim.y) >> 3;
  int swz = (L & 7) * qc + (L >> 3);
  int m0 = (swz % gx) * 128, n0 = (swz / gx) * BN;
  f32x4 acc[4][NT] = {};
  int lr = lane >> 3;
  int cb = (lane & 7) << 4;
  int sws = cb ^ (lr << 4);
  const char* pA = (const char*)(A + (size_t)m0 * lda) + (size_t)(w * 8 + lr) * (lda * 2) + sws;
  const char* pB = (const char*)(Wt + (size_t)n0 * ldb) + (size_t)(w * 8 + lr) * (ldb * 2) + sws;
  char* dA = (char*)As + w * 1024;
  char* dB = (char*)Bs + w * 1024;
  int arow = wm * 64 + (lane & 15);
  int brow = wn * NBAND + (lane & 15);
  int e0 = (lane >> 4) * 8;
  for (int c = 0; c < kOuter; ++c) {
    #pragma unroll
    for (int kt = 0; kt < NK; ++kt) {
      __syncthreads();
      #pragma unroll
      for (int i = 0; i < 4; ++i)
        __builtin_amdgcn_global_load_lds((gvoid_t*)(pA + (size_t)i * 32 * (lda * 2)),
                                         (lvoid_t*)(dA + i * 4096), 16, 0, 0);
      #pragma unroll
      for (int i = 0; i < BN / 32; ++i)
        __builtin_amdgcn_global_load_lds((gvoid_t*)(pB + (size_t)i * 32 * (ldb * 2)),
                                         (lvoid_t*)(dB + i * 4096), 16, 0, 0);
      pA += 128; pB += 128;
      __syncthreads();   // compiler emits vmcnt(0) drain (staged data ready)
      #pragma unroll
      for (int kk = 0; kk < 2; ++kk) {
        bf16x8 af[4], bfr[NT];
        #pragma unroll
        for (int mt = 0; mt < 4; ++mt) af[mt] = ldsfrag(As, arow + mt * 16, kk * 32 + e0);
        #pragma unroll
        for (int nt = 0; nt < NT; ++nt) bfr[nt] = ldsfrag(Bs, brow + nt * 16, kk * 32 + e0);
        #pragma unroll
        for (int mt = 0; mt < 4; ++mt)
          #pragma unroll
          for (int nt = 0; nt < NT; ++nt)
            acc[mt][nt] = MFMA(af[mt], bfr[nt], acc[mt][nt]);
      }
    }
  }
  int rbase = m0 + wm * 64 + ((lane >> 4) << 2);
  int cbase = n0 + wn * NBAND + (lane & 15);
  if constexpr (MODE == 0) {
    int which = n0 / 768;
    u16* dstb = which == 0 ? qb : (which == 1 ? kb : vb);
    int cloc = cbase - which * 768;
    #pragma unroll
    for (int mt = 0; mt < 4; ++mt) {
      #pragma unroll
      for (int nt = 0; nt < NT; ++nt) {
        int rr = cloc + nt * 16;
        int h = rr >> 6, e = rr & 63;
        #pragma unroll
        for (int reg = 0; reg < 4; ++reg) {
          int row = rbase + mt * 16 + reg;
          int b = row >> 10, s = row & 1023;
          dstb[((size_t)(b * 12 + h) * 1024 + s) * 64 + e] = f2bf(acc[mt][nt][reg]);
        }
      }
    }
  } else if constexpr (MODE == 2) {
    #pragma unroll
    for (int mt = 0; mt < 4; ++mt) {
      #pragma unroll
      for (int nt = 0; nt < NT; ++nt) {
        int col = cbase + nt * 16;
        float bb = bias[col];
        #pragma unroll
        for (int reg = 0; reg < 4; ++reg) {
          int row = rbase + mt * 16 + reg;
          float t = acc[mt][nt][reg] + bb;
          float u = t * fmaf(t * t, 0.044715f, 1.0f);
          float ex = __builtin_amdgcn_exp2f(u * -2.3022156f);
          float g = t * __builtin_amdgcn_rcpf(1.0f + ex);
          outb[(size_t)row * 3072 + col] = f2bf(g);
        }
      }
    }
  } else {
    #pragma unroll
    for (int mt = 0; mt < 4; ++mt) {
      #pragma unroll
      for (int nt = 0; nt < NT; ++nt) {
        int col = cbase + nt * 16;
        float bb = (MODE == 3) ? bias[col] : 0.0f;
        #pragma unroll
        for (int reg = 0; reg < 4; ++reg) {
          int row = rbase + mt * 16 + reg;
          size_t idx = (size_t)row * 768 + col;
          float nv = xf[idx] + acc[mt][nt][reg] + bb;
          xf[idx] = nv;
          if (MODE == 3 && outf) outf[idx] = nv;
        }
      }
    }
  }
}

// ---------------------------------------------------------------------------
// flash128: Q-block 128 (two 64-row halves share staged K/V AND the K-frag
// ds_reads). Fixed-shift softmax (exact), l = P@ones via MFMA, double-
// buffered K/V, P-tile LDS reused across halves. XCD swizzle: each XCD owns
// 12 consecutive bh (KV working set 12*256KB=3MB ~ L2).
// q,k: [bh][s][64] ; vt: [bh][e][s] ; o: [b,s, head*64+e]
// ---------------------------------------------------------------------------
__global__ __launch_bounds__(256) void flash128(
    const u16* __restrict__ q, const u16* __restrict__ k, const u16* __restrict__ vt,
    const int* __restrict__ kmask, u16* __restrict__ o) {
  __shared__ alignas(16) u16 Ks[2][64 * 64];
  __shared__ alignas(16) u16 Vs[2][64 * 64];
  __shared__ alignas(16) u16 Ps[64 * 64];
  int tid = threadIdx.x, lane = tid & 63, w = tid >> 6;
  int lc = lane & 15;
  // grid (96, 8): L = y*96+x; swizzle so XCD k gets bh in [12k, 12k+12)
  int L = blockIdx.y * 96 + blockIdx.x;
  int swz = (L & 7) * 96 + (L >> 3);
  int bh = swz >> 3, q0 = (swz & 7) * 128;
  int b = bh / 12, hd = bh % 12;

  stage64(q + ((size_t)bh * 1024 + q0) * 64, 64, Ps, 64, tid);
  stage64(q + ((size_t)bh * 1024 + q0 + 64) * 64, 64, Ks[0], 64, tid);
  __syncthreads();
  int qrow = w * 16 + lc;
  int e0 = (lane >> 4) * 8;
  bf16x8 aq[2][2];
  aq[0][0] = ldsfrag(Ps, qrow, e0);
  aq[0][1] = ldsfrag(Ps, qrow, 32 + e0);
  aq[1][0] = ldsfrag(Ks[0], qrow, e0);
  aq[1][1] = ldsfrag(Ks[0], qrow, 32 + e0);
  __syncthreads();   // all Q reads done before Ks[0] is overwritten

  bf16x8 ones;
  #pragma unroll
  for (int j = 0; j < 8; ++j) ones[j] = (__bf16)1.0f;

  f32x4 oacc[2][4] = {};
  f32x4 lacc[2] = {};
  const float SCL = 0.125f * 1.44269504f;
  const float SH = -3.0f * 1.44269504f;
  int prow_base = w * 16 + ((lane >> 4) << 2);

  stage64(k + (size_t)bh * 1024 * 64, 64, Ks[0], 64, tid);
  stage64(vt + (size_t)bh * 64 * 1024, 1024, Vs[0], 64, tid);

  for (int kt = 0; kt < 16; ++kt) {
    asm volatile("s_waitcnt vmcnt(0)" ::: "memory");
    __builtin_amdgcn_sched_barrier(0);
    __builtin_amdgcn_s_barrier();
    __builtin_amdgcn_sched_barrier(0);
    const u16* Kc = Ks[kt & 1];
    const u16* Vc = Vs[kt & 1];

    f32x4 sacc[2][4] = {};
    #pragma unroll
    for (int nt = 0; nt < 4; ++nt) {
      bf16x8 bk0 = ldsfrag(Kc, nt * 16 + lc, e0);
      bf16x8 bk1 = ldsfrag(Kc, nt * 16 + lc, 32 + e0);
      sacc[0][nt] = MFMA(aq[0][0], bk0, sacc[0][nt]);
      sacc[0][nt] = MFMA(aq[0][1], bk1, sacc[0][nt]);
      sacc[1][nt] = MFMA(aq[1][0], bk0, sacc[1][nt]);
      sacc[1][nt] = MFMA(aq[1][1], bk1, sacc[1][nt]);
    }

    if (kt + 1 < 16) {
      stage64(k + ((size_t)bh * 1024 + (kt + 1) * 64) * 64, 64, Ks[(kt + 1) & 1], 64, tid);
      stage64(vt + (size_t)bh * 64 * 1024 + (kt + 1) * 64, 1024, Vs[(kt + 1) & 1], 64, tid);
    }

    float mkv[4];
    #pragma unroll
    for (int nt = 0; nt < 4; ++nt)
      mkv[nt] = kmask[b * 1024 + kt * 64 + nt * 16 + lc] ? SH : -1e30f;

    #pragma unroll
    for (int h = 0; h < 2; ++h) {
      #pragma unroll
      for (int nt = 0; nt < 4; ++nt) {
        int c = nt * 16 + lc;
        #pragma unroll
        for (int r = 0; r < 4; ++r) {
          float p = __builtin_amdgcn_exp2f(fmaf(sacc[h][nt][r], SCL, mkv[nt]));
          int prow = prow_base + r;
          int boff = prow * 128 + ((c << 1) ^ ((prow & 7) << 4));
          *(u16*)((char*)Ps + boff) = f2bf(p);
        }
      }
      bf16x8 ap0 = ldsfrag(Ps, qrow, e0);
      bf16x8 ap1 = ldsfrag(Ps, qrow, 32 + e0);
      lacc[h] = MFMA(ap0, ones, lacc[h]);
      lacc[h] = MFMA(ap1, ones, lacc[h]);
      #pragma unroll
      for (int et = 0; et < 4; ++et) {
        bf16x8 bv = ldsfrag(Vc, et * 16 + lc, e0);
        oacc[h][et] = MFMA(ap0, bv, oacc[h][et]);
      }
      #pragma unroll
      for (int et = 0; et < 4; ++et) {
        bf16x8 bv = ldsfrag(Vc, et * 16 + lc, 32 + e0);
        oacc[h][et] = MFMA(ap1, bv, oacc[h][et]);
      }
    }
  }

  #pragma unroll
  for (int h = 0; h < 2; ++h) {
    float rl[4];
    #pragma unroll
    for (int r = 0; r < 4; ++r) rl[r] = __builtin_amdgcn_rcpf(lacc[h][r]);
    int orow_base = q0 + h * 64 + prow_base;
    #pragma unroll
    for (int et = 0; et < 4; ++et) {
      int e = et * 16 + lc;
      #pragma unroll
      for (int r = 0; r < 4; ++r) {
        int row = orow_base + r;
        o[((size_t)(b * 1024 + row)) * 768 + hd * 64 + e] = f2bf(oacc[h][et][r] * rl[r]);
      }
    }
  }
}

// ---------------------------------------------------------------------------
extern "C" void kernel_launch(void* const* d_in, const int* in_sizes, int n_in,
                              void* d_out, int out_size, void* d_ws, size_t ws_size,
                              hipStream_t stream) {
  const int* tokens = (const int*)d_in[0];
  const int* kmask = (const int*)d_in[1];
  const float* emb = (const float*)d_in[2];
  const float* pe = (const float*)d_in[3];
  const float* ln1_s = (const float*)d_in[4];
  const float* ln1_b = (const float*)d_in[5];
  const float* wq = (const float*)d_in[6];
  const float* wk = (const float*)d_in[7];
  const float* wv = (const float*)d_in[8];
  const float* wo = (const float*)d_in[9];
  const float* ln2_s = (const float*)d_in[10];
  const float* ln2_b = (const float*)d_in[11];
  const float* w1 = (const float*)d_in[12];
  const float* b1 = (const float*)d_in[13];
  const float* w2 = (const float*)d_in[14];
  const float* b2 = (const float*)d_in[15];

  char* ws = (char*)d_ws;
  float* xf = (float*)ws;                       // 8192*768*4
  u16* xn   = (u16*)(ws + 25165824);
  u16* qb   = (u16*)(ws + 37748736);
  u16* kb   = (u16*)(ws + 50331648);
  u16* vb   = (u16*)(ws + 62914560);
  u16* vtb  = (u16*)(ws + 75497472);
  u16* ob   = (u16*)(ws + 88080384);
  u16* ffh  = (u16*)(ws + 100663296);           // 8192*3072*2

  const size_t SZ_QKV = (size_t)2304 * 768;
  const size_t SZ_O   = (size_t)768 * 768;
  const size_t SZ_F1  = (size_t)3072 * 768;
  const size_t SZ_F2  = (size_t)768 * 3072;
  const size_t NEED = 150994944 + 2 * 6 * (SZ_QKV + SZ_O + SZ_F1 + SZ_F2);
  bool pre = ws_size >= NEED;
  int nz = pre ? 6 : 1;
  u16* wqkvt = (u16*)(ws + 150994944);
  u16* wot   = wqkvt + (size_t)nz * SZ_QKV;
  u16* w1t   = wot + (size_t)nz * SZ_O;
  u16* w2t   = w1t + (size_t)nz * SZ_F1;

  embed_kernel<<<8192, 192, 0, stream>>>(tokens, emb, pe, xf);

  if (pre) {
    convqkvT_kernel<<<dim3(72, 24, 6), 256, 0, stream>>>(wq, wk, wv, wqkvt, 589824LL, (long long)SZ_QKV);
    convT_kernel<<<dim3(24, 24, 6), 256, 0, stream>>>(wo, wot, 768, 768, 589824LL, (long long)SZ_O);
    convT_kernel<<<dim3(96, 24, 6), 256, 0, stream>>>(w1, w1t, 3072, 768, 2359296LL, (long long)SZ_F1);
    convT_kernel<<<dim3(24, 96, 6), 256, 0, stream>>>(w2, w2t, 768, 3072, 2359296LL, (long long)SZ_F2);
  }

  for (int l = 0; l < 6; ++l) {
    size_t woff_qkv = (size_t)l * 12 * 768 * 64;
    size_t woff_o = (size_t)l * 768 * 768;
    size_t woff_ff = (size_t)l * 768 * 3072;
    const u16* wt_qkv_l = wqkvt + (pre ? (size_t)l * SZ_QKV : 0);
    const u16* wt_o_l   = wot   + (pre ? (size_t)l * SZ_O   : 0);
    const u16* wt_1_l   = w1t   + (pre ? (size_t)l * SZ_F1  : 0);
    const u16* wt_2_l   = w2t   + (pre ? (size_t)l * SZ_F2  : 0);

    if (!pre) {
      convqkvT_kernel<<<dim3(72, 24, 1), 256, 0, stream>>>(wq + woff_qkv, wk + woff_qkv, wv + woff_qkv, (u16*)wt_qkv_l, 0LL, 0LL);
      convT_kernel<<<dim3(24, 24, 1), 256, 0, stream>>>(wo + woff_o, (u16*)wt_o_l, 768, 768, 0LL, 0LL);
      convT_kernel<<<dim3(96, 24, 1), 256, 0, stream>>>(w1 + woff_ff, (u16*)wt_1_l, 3072, 768, 0LL, 0LL);
      convT_kernel<<<dim3(24, 96, 1), 256, 0, stream>>>(w2 + woff_ff, (u16*)wt_2_l, 768, 3072, 0LL, 0LL);
    }

    ln_kernel<<<2048, 256, 0, stream>>>(xf, ln1_s + l * 768, ln1_b + l * 768, xn);
    gemm128<0, 6, 128><<<dim3(64, 18, 1), 256, 0, stream>>>(xn, 768, wt_qkv_l, 768, 2, nullptr, nullptr, nullptr, qb, kb, vb, nullptr);
    transpose_v_kernel<<<dim3(96, 16), 256, 0, stream>>>(vb, vtb);
    flash128<<<dim3(96, 8), 256, 0, stream>>>(qb, kb, vtb, kmask, ob);
    gemm128<1, 6, 64><<<dim3(64, 12, 1), 256, 0, stream>>>(ob, 768, wt_o_l, 768, 2, xf, nullptr, nullptr, nullptr, nullptr, nullptr, nullptr);
    ln_kernel<<<2048, 256, 0, stream>>>(xf, ln2_s + l * 768, ln2_b + l * 768, xn);
    gemm128<2, 6, 128><<<dim3(64, 24, 1), 256, 0, stream>>>(xn, 768, wt_1_l, 768, 2, nullptr, ffh, b1 + l * 3072, nullptr, nullptr, nullptr, nullptr);
    gemm128<3, 6, 64><<<dim3(64, 12, 1), 256, 0, stream>>>(ffh, 3072, wt_2_l, 3072, 8, xf, nullptr, b2 + l * 768, nullptr, nullptr, nullptr,
                                                           (l == 5) ? (float*)d_out : nullptr);
  }
}

// Round 12
// 1540.082 us; speedup vs baseline: 1.2603x; 1.2603x over previous
//
#include <hip/hip_runtime.h>
#include <math.h>

typedef unsigned short u16;
typedef unsigned int u32;
typedef __attribute__((ext_vector_type(8))) __bf16 bf16x8;
typedef __attribute__((ext_vector_type(4))) float f32x4;
typedef __attribute__((ext_vector_type(8))) unsigned short ushort8v;
typedef __attribute__((ext_vector_type(4))) float float4v;
typedef __attribute__((ext_vector_type(4))) unsigned short u16x4;

typedef const __attribute__((address_space(1))) void gvoid_t;
typedef __attribute__((address_space(3))) void lvoid_t;

#define MFMA(a, b, c) __builtin_amdgcn_mfma_f32_16x16x32_bf16((a), (b), (c), 0, 0, 0)

// native RNE f32->bf16
__device__ __forceinline__ u16 f2bf(float f) {
  __bf16 h = (__bf16)f;
  return __builtin_bit_cast(u16, h);
}

// ---------------------------------------------------------------------------
// [rows][64] bf16 tiles (128B rows), XOR-swizzled source + swizzled reads
// (involution (r&7)<<4) -> conflict-free ds_read_b128. (proven 0-conflict)
// ---------------------------------------------------------------------------
__device__ __forceinline__ void stage64(const u16* g, int ldg, u16* lds, int rows, int tid) {
  int w = tid >> 6, l = tid & 63;
  int lr = l >> 3;
  int cb = (l & 7) << 4;
  for (int it = 0; it < rows; it += 32) {
    int rbase = it + w * 8;
    int r = rbase + lr;
    int scb = cb ^ ((r & 7) << 4);
    const char* gp = (const char*)(g + (size_t)r * ldg) + scb;
    char* lp = (char*)lds + (size_t)rbase * 128;
    __builtin_amdgcn_global_load_lds((gvoid_t*)gp, (lvoid_t*)lp, 16, 0, 0);
  }
}

__device__ __forceinline__ bf16x8 ldsfrag(const u16* base, int row, int e0) {
  int boff = row * 128 + (((e0) << 1) ^ ((row & 7) << 4));
  return *(const bf16x8*)((const char*)base + boff);
}

// ---------------------------------------------------------------------------
// embed
// ---------------------------------------------------------------------------
__global__ void embed_kernel(const int* __restrict__ tok, const float* __restrict__ emb,
                             const float* __restrict__ pe, float* __restrict__ xf) {
  int row = blockIdx.x;
  int tid = threadIdx.x;              // 192
  int t = tok[row];
  int spos = row & 1023;
  float4v e = ((const float4v*)(emb + (size_t)t * 768))[tid];
  float4v p = ((const float4v*)(pe + (size_t)spos * 768))[tid];
  float4v r;
  r.x = e.x + p.x; r.y = e.y + p.y; r.z = e.z + p.z; r.w = e.w + p.w;
  ((float4v*)(xf + (size_t)row * 768))[tid] = r;
}

// ---------------------------------------------------------------------------
// layernorm: one WAVE per row (4 rows / 256-thr block), pure shuffle
// reduction — no LDS, no __syncthreads. (r10 proven win)
// ---------------------------------------------------------------------------
__global__ __launch_bounds__(256) void ln_kernel(const float* __restrict__ x,
                                                 const float* __restrict__ sc,
                                                 const float* __restrict__ bi,
                                                 u16* __restrict__ out) {
  int w = threadIdx.x >> 6, lane = threadIdx.x & 63;
  int row = blockIdx.x * 4 + w;
  const float* xr = x + (size_t)row * 768;
  float4v v[3];
  #pragma unroll
  for (int c = 0; c < 3; ++c) v[c] = ((const float4v*)xr)[c * 64 + lane];
  float s = 0.0f, s2 = 0.0f;
  #pragma unroll
  for (int c = 0; c < 3; ++c) {
    s += v[c].x + v[c].y + v[c].z + v[c].w;
    s2 += v[c].x * v[c].x + v[c].y * v[c].y + v[c].z * v[c].z + v[c].w * v[c].w;
  }
  #pragma unroll
  for (int off = 32; off >= 1; off >>= 1) {
    s += __shfl_down(s, off);
    s2 += __shfl_down(s2, off);
  }
  s = __shfl(s, 0);
  s2 = __shfl(s2, 0);
  float m = s * (1.0f / 768.0f);
  float var = s2 * (1.0f / 768.0f) - m * m;
  float rs = rsqrtf(var + 1e-5f);
  u16* or_ = out + (size_t)row * 768;
  #pragma unroll
  for (int c = 0; c < 3; ++c) {
    float4v sv = ((const float4v*)sc)[c * 64 + lane];
    float4v bv = ((const float4v*)bi)[c * 64 + lane];
    u16x4 ov;
    ov.x = f2bf((v[c].x - m) * rs * sv.x + bv.x);
    ov.y = f2bf((v[c].y - m) * rs * sv.y + bv.y);
    ov.z = f2bf((v[c].z - m) * rs * sv.z + bv.z);
    ov.w = f2bf((v[c].w - m) * rs * sv.w + bv.w);
    ((u16x4*)or_)[c * 64 + lane] = ov;
  }
}

// ---------------------------------------------------------------------------
// weight converters: f32 [K][N] -> bf16 [N][K]
// ---------------------------------------------------------------------------
__global__ void convT_kernel(const float* __restrict__ src, u16* __restrict__ dst,
                             int N, int K, long long sz, long long dz) {
  src += (size_t)blockIdx.z * sz;
  dst += (size_t)blockIdx.z * dz;
  __shared__ float t[32][33];
  int n0 = blockIdx.x * 32, k0 = blockIdx.y * 32;
  int tid = threadIdx.x;
  int tx = tid & 31, ty = tid >> 5;
  for (int r = ty; r < 32; r += 8) t[r][tx] = src[(size_t)(k0 + r) * N + n0 + tx];
  __syncthreads();
  for (int r = ty; r < 32; r += 8) dst[(size_t)(n0 + r) * K + k0 + tx] = f2bf(t[tx][r]);
}

__global__ void convqkvT_kernel(const float* __restrict__ wq, const float* __restrict__ wk,
                                const float* __restrict__ wv, u16* __restrict__ dst,
                                long long wz, long long dz) {
  __shared__ float t[32][33];
  int n0 = blockIdx.x * 32, k0 = blockIdx.y * 32;
  int which = n0 / 768;
  int r0 = n0 % 768;
  int h = r0 >> 6, e0 = r0 & 63;
  const float* src = which == 0 ? wq : (which == 1 ? wk : wv);
  src += (size_t)blockIdx.z * wz;
  dst += (size_t)blockIdx.z * dz;
  int tid = threadIdx.x;
  int tx = tid & 31, ty = tid >> 5;
  for (int r = ty; r < 32; r += 8) t[r][tx] = src[(size_t)(h * 768 + k0 + r) * 64 + e0 + tx];
  __syncthreads();
  for (int r = ty; r < 32; r += 8) dst[(size_t)(n0 + r) * 768 + k0 + tx] = f2bf(t[tx][r]);
}

// ---------------------------------------------------------------------------
// v [bh][s][e] -> vt [bh][e][s]  (round-6 proven)
// ---------------------------------------------------------------------------
__global__ void transpose_v_kernel(const u16* __restrict__ v, u16* __restrict__ vt) {
  __shared__ u16 t[64][72];
  int bh = blockIdx.x, sc = blockIdx.y;
  int tid = threadIdx.x;
  const u16* src = v + ((size_t)bh * 1024 + sc * 64) * 64;
  int sl = tid >> 2, e0 = (tid & 3) * 16;
  ushort8v a = *(const ushort8v*)(src + (size_t)sl * 64 + e0);
  ushort8v b = *(const ushort8v*)(src + (size_t)sl * 64 + e0 + 8);
  #pragma unroll
  for (int j = 0; j < 8; ++j) t[sl][e0 + j] = a[j];
  #pragma unroll
  for (int j = 0; j < 8; ++j) t[sl][e0 + 8 + j] = b[j];
  __syncthreads();
  int e = tid >> 2, s0 = (tid & 3) * 16;
  ushort8v o0, o1;
  #pragma unroll
  for (int j = 0; j < 8; ++j) o0[j] = t[s0 + j][e];
  #pragma unroll
  for (int j = 0; j < 8; ++j) o1[j] = t[s0 + 8 + j][e];
  u16* dst = vt + ((size_t)bh * 64 + e) * 1024 + sc * 64 + s0;
  *(ushort8v*)dst = o0;
  *(ushort8v*)(dst + 8) = o1;
}

// ---------------------------------------------------------------------------
// gemm128 (round-6 proven loop, NO grid swizzle — r11 showed the default
// x-fastest round-robin already gives each XCD blocks sharing a B-strip;
// remapping destroyed L2 locality, FETCH 55->273 MB): C[M,N] = A[M,K]*Wt[N,K],
// 128xBN tile, BK=64, 4 waves, 2-barrier loop, global_load_lds width-16,
// both-sides XOR swizzle, hoisted addresses, NK=6 unroll x kOuter chunks.
// BN=128: wave tile 64x64. BN=64: wave tile 64x32 (N=768 GEMMs, 768 blocks).
// MODE 0: QKV scatter  MODE 1: xf += C  MODE 2: gelu(C+b1)->bf16
// MODE 3: xf += C + b2 (+ optional outf f32 copy)
// ---------------------------------------------------------------------------
template <int MODE, int NK, int BN>
__global__ __launch_bounds__(256) void gemm128(
    const u16* __restrict__ A, int lda, const u16* __restrict__ Wt, int ldb, int kOuter,
    float* __restrict__ xf, u16* __restrict__ outb, const float* __restrict__ bias,
    u16* __restrict__ qb, u16* __restrict__ kb, u16* __restrict__ vb,
    float* __restrict__ outf) {
  constexpr int NT = BN / 32;                 // B frags per wave (4 or 2)
  constexpr int NBAND = BN / 2;               // wave N width
  __shared__ alignas(16) u16 As[128 * 64];
  __shared__ alignas(16) u16 Bs[BN * 64];
  int tid = threadIdx.x, lane = tid & 63, w = tid >> 6;
  int wm = w >> 1, wn = w & 1;
  int m0 = blockIdx.x * 128, n0 = blockIdx.y * BN;
  f32x4 acc[4][NT] = {};
  int lr = lane >> 3;
  int cb = (lane & 7) << 4;
  int sws = cb ^ (lr << 4);
  const char* pA = (const char*)(A + (size_t)m0 * lda) + (size_t)(w * 8 + lr) * (lda * 2) + sws;
  const char* pB = (const char*)(Wt + (size_t)n0 * ldb) + (size_t)(w * 8 + lr) * (ldb * 2) + sws;
  char* dA = (char*)As + w * 1024;
  char* dB = (char*)Bs + w * 1024;
  int arow = wm * 64 + (lane & 15);
  int brow = wn * NBAND + (lane & 15);
  int e0 = (lane >> 4) * 8;
  for (int c = 0; c < kOuter; ++c) {
    #pragma unroll
    for (int kt = 0; kt < NK; ++kt) {
      __syncthreads();
      #pragma unroll
      for (int i = 0; i < 4; ++i)
        __builtin_amdgcn_global_load_lds((gvoid_t*)(pA + (size_t)i * 32 * (lda * 2)),
                                         (lvoid_t*)(dA + i * 4096), 16, 0, 0);
      #pragma unroll
      for (int i = 0; i < BN / 32; ++i)
        __builtin_amdgcn_global_load_lds((gvoid_t*)(pB + (size_t)i * 32 * (ldb * 2)),
                                         (lvoid_t*)(dB + i * 4096), 16, 0, 0);
      pA += 128; pB += 128;
      __syncthreads();   // compiler emits vmcnt(0) drain (staged data ready)
      #pragma unroll
      for (int kk = 0; kk < 2; ++kk) {
        bf16x8 af[4], bfr[NT];
        #pragma unroll
        for (int mt = 0; mt < 4; ++mt) af[mt] = ldsfrag(As, arow + mt * 16, kk * 32 + e0);
        #pragma unroll
        for (int nt = 0; nt < NT; ++nt) bfr[nt] = ldsfrag(Bs, brow + nt * 16, kk * 32 + e0);
        #pragma unroll
        for (int mt = 0; mt < 4; ++mt)
          #pragma unroll
          for (int nt = 0; nt < NT; ++nt)
            acc[mt][nt] = MFMA(af[mt], bfr[nt], acc[mt][nt]);
      }
    }
  }
  int rbase = m0 + wm * 64 + ((lane >> 4) << 2);
  int cbase = n0 + wn * NBAND + (lane & 15);
  if constexpr (MODE == 0) {
    int which = n0 / 768;
    u16* dstb = which == 0 ? qb : (which == 1 ? kb : vb);
    int cloc = cbase - which * 768;
    #pragma unroll
    for (int mt = 0; mt < 4; ++mt) {
      #pragma unroll
      for (int nt = 0; nt < NT; ++nt) {
        int rr = cloc + nt * 16;
        int h = rr >> 6, e = rr & 63;
        #pragma unroll
        for (int reg = 0; reg < 4; ++reg) {
          int row = rbase + mt * 16 + reg;
          int b = row >> 10, s = row & 1023;
          dstb[((size_t)(b * 12 + h) * 1024 + s) * 64 + e] = f2bf(acc[mt][nt][reg]);
        }
      }
    }
  } else if constexpr (MODE == 2) {
    #pragma unroll
    for (int mt = 0; mt < 4; ++mt) {
      #pragma unroll
      for (int nt = 0; nt < NT; ++nt) {
        int col = cbase + nt * 16;
        float bb = bias[col];
        #pragma unroll
        for (int reg = 0; reg < 4; ++reg) {
          int row = rbase + mt * 16 + reg;
          float t = acc[mt][nt][reg] + bb;
          float u = t * fmaf(t * t, 0.044715f, 1.0f);
          float ex = __builtin_amdgcn_exp2f(u * -2.3022156f);
          float g = t * __builtin_amdgcn_rcpf(1.0f + ex);
          outb[(size_t)row * 3072 + col] = f2bf(g);
        }
      }
    }
  } else {
    #pragma unroll
    for (int mt = 0; mt < 4; ++mt) {
      #pragma unroll
      for (int nt = 0; nt < NT; ++nt) {
        int col = cbase + nt * 16;
        float bb = (MODE == 3) ? bias[col] : 0.0f;
        #pragma unroll
        for (int reg = 0; reg < 4; ++reg) {
          int row = rbase + mt * 16 + reg;
          size_t idx = (size_t)row * 768 + col;
          float nv = xf[idx] + acc[mt][nt][reg] + bb;
          xf[idx] = nv;
          if (MODE == 3 && outf) outf[idx] = nv;
        }
      }
    }
  }
}

// ---------------------------------------------------------------------------
// flash128: Q-block 128 (two 64-row halves share staged K/V AND the K-frag
// ds_reads). Fixed-shift softmax (exact), l = P@ones via MFMA, double-
// buffered K/V, P-tile LDS reused across halves. No grid swizzle (r11).
// q,k: [bh][s][64] ; vt: [bh][e][s] ; o: [b,s, head*64+e]
// ---------------------------------------------------------------------------
__global__ __launch_bounds__(256) void flash128(
    const u16* __restrict__ q, const u16* __restrict__ k, const u16* __restrict__ vt,
    const int* __restrict__ kmask, u16* __restrict__ o) {
  __shared__ alignas(16) u16 Ks[2][64 * 64];
  __shared__ alignas(16) u16 Vs[2][64 * 64];
  __shared__ alignas(16) u16 Ps[64 * 64];
  int tid = threadIdx.x, lane = tid & 63, w = tid >> 6;
  int lc = lane & 15;
  int bh = blockIdx.x, q0 = blockIdx.y * 128;
  int b = bh / 12, hd = bh % 12;

  stage64(q + ((size_t)bh * 1024 + q0) * 64, 64, Ps, 64, tid);
  stage64(q + ((size_t)bh * 1024 + q0 + 64) * 64, 64, Ks[0], 64, tid);
  __syncthreads();
  int qrow = w * 16 + lc;
  int e0 = (lane >> 4) * 8;
  bf16x8 aq[2][2];
  aq[0][0] = ldsfrag(Ps, qrow, e0);
  aq[0][1] = ldsfrag(Ps, qrow, 32 + e0);
  aq[1][0] = ldsfrag(Ks[0], qrow, e0);
  aq[1][1] = ldsfrag(Ks[0], qrow, 32 + e0);
  __syncthreads();   // all Q reads done before Ks[0] is overwritten

  bf16x8 ones;
  #pragma unroll
  for (int j = 0; j < 8; ++j) ones[j] = (__bf16)1.0f;

  f32x4 oacc[2][4] = {};
  f32x4 lacc[2] = {};
  const float SCL = 0.125f * 1.44269504f;
  const float SH = -3.0f * 1.44269504f;
  int prow_base = w * 16 + ((lane >> 4) << 2);

  stage64(k + (size_t)bh * 1024 * 64, 64, Ks[0], 64, tid);
  stage64(vt + (size_t)bh * 64 * 1024, 1024, Vs[0], 64, tid);

  for (int kt = 0; kt < 16; ++kt) {
    asm volatile("s_waitcnt vmcnt(0)" ::: "memory");
    __builtin_amdgcn_sched_barrier(0);
    __builtin_amdgcn_s_barrier();
    __builtin_amdgcn_sched_barrier(0);
    const u16* Kc = Ks[kt & 1];
    const u16* Vc = Vs[kt & 1];

    f32x4 sacc[2][4] = {};
    #pragma unroll
    for (int nt = 0; nt < 4; ++nt) {
      bf16x8 bk0 = ldsfrag(Kc, nt * 16 + lc, e0);
      bf16x8 bk1 = ldsfrag(Kc, nt * 16 + lc, 32 + e0);
      sacc[0][nt] = MFMA(aq[0][0], bk0, sacc[0][nt]);
      sacc[0][nt] = MFMA(aq[0][1], bk1, sacc[0][nt]);
      sacc[1][nt] = MFMA(aq[1][0], bk0, sacc[1][nt]);
      sacc[1][nt] = MFMA(aq[1][1], bk1, sacc[1][nt]);
    }

    if (kt + 1 < 16) {
      stage64(k + ((size_t)bh * 1024 + (kt + 1) * 64) * 64, 64, Ks[(kt + 1) & 1], 64, tid);
      stage64(vt + (size_t)bh * 64 * 1024 + (kt + 1) * 64, 1024, Vs[(kt + 1) & 1], 64, tid);
    }

    float mkv[4];
    #pragma unroll
    for (int nt = 0; nt < 4; ++nt)
      mkv[nt] = kmask[b * 1024 + kt * 64 + nt * 16 + lc] ? SH : -1e30f;

    #pragma unroll
    for (int h = 0; h < 2; ++h) {
      #pragma unroll
      for (int nt = 0; nt < 4; ++nt) {
        int c = nt * 16 + lc;
        #pragma unroll
        for (int r = 0; r < 4; ++r) {
          float p = __builtin_amdgcn_exp2f(fmaf(sacc[h][nt][r], SCL, mkv[nt]));
          int prow = prow_base + r;
          int boff = prow * 128 + ((c << 1) ^ ((prow & 7) << 4));
          *(u16*)((char*)Ps + boff) = f2bf(p);
        }
      }
      bf16x8 ap0 = ldsfrag(Ps, qrow, e0);
      bf16x8 ap1 = ldsfrag(Ps, qrow, 32 + e0);
      lacc[h] = MFMA(ap0, ones, lacc[h]);
      lacc[h] = MFMA(ap1, ones, lacc[h]);
      #pragma unroll
      for (int et = 0; et < 4; ++et) {
        bf16x8 bv = ldsfrag(Vc, et * 16 + lc, e0);
        oacc[h][et] = MFMA(ap0, bv, oacc[h][et]);
      }
      #pragma unroll
      for (int et = 0; et < 4; ++et) {
        bf16x8 bv = ldsfrag(Vc, et * 16 + lc, 32 + e0);
        oacc[h][et] = MFMA(ap1, bv, oacc[h][et]);
      }
    }
  }

  #pragma unroll
  for (int h = 0; h < 2; ++h) {
    float rl[4];
    #pragma unroll
    for (int r = 0; r < 4; ++r) rl[r] = __builtin_amdgcn_rcpf(lacc[h][r]);
    int orow_base = q0 + h * 64 + prow_base;
    #pragma unroll
    for (int et = 0; et < 4; ++et) {
      int e = et * 16 + lc;
      #pragma unroll
      for (int r = 0; r < 4; ++r) {
        int row = orow_base + r;
        o[((size_t)(b * 1024 + row)) * 768 + hd * 64 + e] = f2bf(oacc[h][et][r] * rl[r]);
      }
    }
  }
}

// ---------------------------------------------------------------------------
extern "C" void kernel_launch(void* const* d_in, const int* in_sizes, int n_in,
                              void* d_out, int out_size, void* d_ws, size_t ws_size,
                              hipStream_t stream) {
  const int* tokens = (const int*)d_in[0];
  const int* kmask = (const int*)d_in[1];
  const float* emb = (const float*)d_in[2];
  const float* pe = (const float*)d_in[3];
  const float* ln1_s = (const float*)d_in[4];
  const float* ln1_b = (const float*)d_in[5];
  const float* wq = (const float*)d_in[6];
  const float* wk = (const float*)d_in[7];
  const float* wv = (const float*)d_in[8];
  const float* wo = (const float*)d_in[9];
  const float* ln2_s = (const float*)d_in[10];
  const float* ln2_b = (const float*)d_in[11];
  const float* w1 = (const float*)d_in[12];
  const float* b1 = (const float*)d_in[13];
  const float* w2 = (const float*)d_in[14];
  const float* b2 = (const float*)d_in[15];

  char* ws = (char*)d_ws;
  float* xf = (float*)ws;                       // 8192*768*4
  u16* xn   = (u16*)(ws + 25165824);
  u16* qb   = (u16*)(ws + 37748736);
  u16* kb   = (u16*)(ws + 50331648);
  u16* vb   = (u16*)(ws + 62914560);
  u16* vtb  = (u16*)(ws + 75497472);
  u16* ob   = (u16*)(ws + 88080384);
  u16* ffh  = (u16*)(ws + 100663296);           // 8192*3072*2

  const size_t SZ_QKV = (size_t)2304 * 768;
  const size_t SZ_O   = (size_t)768 * 768;
  const size_t SZ_F1  = (size_t)3072 * 768;
  const size_t SZ_F2  = (size_t)768 * 3072;
  const size_t NEED = 150994944 + 2 * 6 * (SZ_QKV + SZ_O + SZ_F1 + SZ_F2);
  bool pre = ws_size >= NEED;
  int nz = pre ? 6 : 1;
  u16* wqkvt = (u16*)(ws + 150994944);
  u16* wot   = wqkvt + (size_t)nz * SZ_QKV;
  u16* w1t   = wot + (size_t)nz * SZ_O;
  u16* w2t   = w1t + (size_t)nz * SZ_F1;

  embed_kernel<<<8192, 192, 0, stream>>>(tokens, emb, pe, xf);

  if (pre) {
    convqkvT_kernel<<<dim3(72, 24, 6), 256, 0, stream>>>(wq, wk, wv, wqkvt, 589824LL, (long long)SZ_QKV);
    convT_kernel<<<dim3(24, 24, 6), 256, 0, stream>>>(wo, wot, 768, 768, 589824LL, (long long)SZ_O);
    convT_kernel<<<dim3(96, 24, 6), 256, 0, stream>>>(w1, w1t, 3072, 768, 2359296LL, (long long)SZ_F1);
    convT_kernel<<<dim3(24, 96, 6), 256, 0, stream>>>(w2, w2t, 768, 3072, 2359296LL, (long long)SZ_F2);
  }

  for (int l = 0; l < 6; ++l) {
    size_t woff_qkv = (size_t)l * 12 * 768 * 64;
    size_t woff_o = (size_t)l * 768 * 768;
    size_t woff_ff = (size_t)l * 768 * 3072;
    const u16* wt_qkv_l = wqkvt + (pre ? (size_t)l * SZ_QKV : 0);
    const u16* wt_o_l   = wot   + (pre ? (size_t)l * SZ_O   : 0);
    const u16* wt_1_l   = w1t   + (pre ? (size_t)l * SZ_F1  : 0);
    const u16* wt_2_l   = w2t   + (pre ? (size_t)l * SZ_F2  : 0);

    if (!pre) {
      convqkvT_kernel<<<dim3(72, 24, 1), 256, 0, stream>>>(wq + woff_qkv, wk + woff_qkv, wv + woff_qkv, (u16*)wt_qkv_l, 0LL, 0LL);
      convT_kernel<<<dim3(24, 24, 1), 256, 0, stream>>>(wo + woff_o, (u16*)wt_o_l, 768, 768, 0LL, 0LL);
      convT_kernel<<<dim3(96, 24, 1), 256, 0, stream>>>(w1 + woff_ff, (u16*)wt_1_l, 3072, 768, 0LL, 0LL);
      convT_kernel<<<dim3(24, 96, 1), 256, 0, stream>>>(w2 + woff_ff, (u16*)wt_2_l, 768, 3072, 0LL, 0LL);
    }

    ln_kernel<<<2048, 256, 0, stream>>>(xf, ln1_s + l * 768, ln1_b + l * 768, xn);
    gemm128<0, 6, 128><<<dim3(64, 18, 1), 256, 0, stream>>>(xn, 768, wt_qkv_l, 768, 2, nullptr, nullptr, nullptr, qb, kb, vb, nullptr);
    transpose_v_kernel<<<dim3(96, 16), 256, 0, stream>>>(vb, vtb);
    flash128<<<dim3(96, 8), 256, 0, stream>>>(qb, kb, vtb, kmask, ob);
    gemm128<1, 6, 64><<<dim3(64, 12, 1), 256, 0, stream>>>(ob, 768, wt_o_l, 768, 2, xf, nullptr, nullptr, nullptr, nullptr, nullptr, nullptr);
    ln_kernel<<<2048, 256, 0, stream>>>(xf, ln2_s + l * 768, ln2_b + l * 768, xn);
    gemm128<2, 6, 128><<<dim3(64, 24, 1), 256, 0, stream>>>(xn, 768, wt_1_l, 768, 2, nullptr, ffh, b1 + l * 3072, nullptr, nullptr, nullptr, nullptr);
    gemm128<3, 6, 64><<<dim3(64, 12, 1), 256, 0, stream>>>(ffh, 3072, wt_2_l, 3072, 8, xf, nullptr, b2 + l * 768, nullptr, nullptr, nullptr,
                                                           (l == 5) ? (float*)d_out : nullptr);
  }
}

// Round 13
// 1450.630 us; speedup vs baseline: 1.3380x; 1.0617x over previous
//
#include <hip/hip_runtime.h>
#include <math.h>

typedef unsigned short u16;
typedef unsigned int u32;
typedef __attribute__((ext_vector_type(8))) __bf16 bf16x8;
typedef __attribute__((ext_vector_type(4))) float f32x4;
typedef __attribute__((ext_vector_type(8))) unsigned short ushort8v;
typedef __attribute__((ext_vector_type(4))) float float4v;
typedef __attribute__((ext_vector_type(4))) unsigned short u16x4;

typedef const __attribute__((address_space(1))) void gvoid_t;
typedef __attribute__((address_space(3))) void lvoid_t;

#define MFMA(a, b, c) __builtin_amdgcn_mfma_f32_16x16x32_bf16((a), (b), (c), 0, 0, 0)

// native RNE f32->bf16
__device__ __forceinline__ u16 f2bf(float f) {
  __bf16 h = (__bf16)f;
  return __builtin_bit_cast(u16, h);
}

// ---------------------------------------------------------------------------
// [rows][64] bf16 tiles (128B rows), XOR-swizzled source + swizzled reads
// (involution (r&7)<<4) -> conflict-free ds_read_b128. (proven 0-conflict)
// ---------------------------------------------------------------------------
__device__ __forceinline__ void stage64(const u16* g, int ldg, u16* lds, int rows, int tid) {
  int w = tid >> 6, l = tid & 63;
  int lr = l >> 3;
  int cb = (l & 7) << 4;
  for (int it = 0; it < rows; it += 32) {
    int rbase = it + w * 8;
    int r = rbase + lr;
    int scb = cb ^ ((r & 7) << 4);
    const char* gp = (const char*)(g + (size_t)r * ldg) + scb;
    char* lp = (char*)lds + (size_t)rbase * 128;
    __builtin_amdgcn_global_load_lds((gvoid_t*)gp, (lvoid_t*)lp, 16, 0, 0);
  }
}

__device__ __forceinline__ bf16x8 ldsfrag(const u16* base, int row, int e0) {
  int boff = row * 128 + (((e0) << 1) ^ ((row & 7) << 4));
  return *(const bf16x8*)((const char*)base + boff);
}

// ---------------------------------------------------------------------------
// embed
// ---------------------------------------------------------------------------
__global__ void embed_kernel(const int* __restrict__ tok, const float* __restrict__ emb,
                             const float* __restrict__ pe, float* __restrict__ xf) {
  int row = blockIdx.x;
  int tid = threadIdx.x;              // 192
  int t = tok[row];
  int spos = row & 1023;
  float4v e = ((const float4v*)(emb + (size_t)t * 768))[tid];
  float4v p = ((const float4v*)(pe + (size_t)spos * 768))[tid];
  float4v r;
  r.x = e.x + p.x; r.y = e.y + p.y; r.z = e.z + p.z; r.w = e.w + p.w;
  ((float4v*)(xf + (size_t)row * 768))[tid] = r;
}

// ---------------------------------------------------------------------------
// layernorm: one WAVE per row (4 rows / 256-thr block), pure shuffle
// reduction — no LDS, no __syncthreads. (r10 proven win)
// ---------------------------------------------------------------------------
__global__ __launch_bounds__(256) void ln_kernel(const float* __restrict__ x,
                                                 const float* __restrict__ sc,
                                                 const float* __restrict__ bi,
                                                 u16* __restrict__ out) {
  int w = threadIdx.x >> 6, lane = threadIdx.x & 63;
  int row = blockIdx.x * 4 + w;
  const float* xr = x + (size_t)row * 768;
  float4v v[3];
  #pragma unroll
  for (int c = 0; c < 3; ++c) v[c] = ((const float4v*)xr)[c * 64 + lane];
  float s = 0.0f, s2 = 0.0f;
  #pragma unroll
  for (int c = 0; c < 3; ++c) {
    s += v[c].x + v[c].y + v[c].z + v[c].w;
    s2 += v[c].x * v[c].x + v[c].y * v[c].y + v[c].z * v[c].z + v[c].w * v[c].w;
  }
  #pragma unroll
  for (int off = 32; off >= 1; off >>= 1) {
    s += __shfl_down(s, off);
    s2 += __shfl_down(s2, off);
  }
  s = __shfl(s, 0);
  s2 = __shfl(s2, 0);
  float m = s * (1.0f / 768.0f);
  float var = s2 * (1.0f / 768.0f) - m * m;
  float rs = rsqrtf(var + 1e-5f);
  u16* or_ = out + (size_t)row * 768;
  #pragma unroll
  for (int c = 0; c < 3; ++c) {
    float4v sv = ((const float4v*)sc)[c * 64 + lane];
    float4v bv = ((const float4v*)bi)[c * 64 + lane];
    u16x4 ov;
    ov.x = f2bf((v[c].x - m) * rs * sv.x + bv.x);
    ov.y = f2bf((v[c].y - m) * rs * sv.y + bv.y);
    ov.z = f2bf((v[c].z - m) * rs * sv.z + bv.z);
    ov.w = f2bf((v[c].w - m) * rs * sv.w + bv.w);
    ((u16x4*)or_)[c * 64 + lane] = ov;
  }
}

// ---------------------------------------------------------------------------
// weight converters: f32 [K][N] -> bf16 [N][K]
// ---------------------------------------------------------------------------
__global__ void convT_kernel(const float* __restrict__ src, u16* __restrict__ dst,
                             int N, int K, long long sz, long long dz) {
  src += (size_t)blockIdx.z * sz;
  dst += (size_t)blockIdx.z * dz;
  __shared__ float t[32][33];
  int n0 = blockIdx.x * 32, k0 = blockIdx.y * 32;
  int tid = threadIdx.x;
  int tx = tid & 31, ty = tid >> 5;
  for (int r = ty; r < 32; r += 8) t[r][tx] = src[(size_t)(k0 + r) * N + n0 + tx];
  __syncthreads();
  for (int r = ty; r < 32; r += 8) dst[(size_t)(n0 + r) * K + k0 + tx] = f2bf(t[tx][r]);
}

__global__ void convqkvT_kernel(const float* __restrict__ wq, const float* __restrict__ wk,
                                const float* __restrict__ wv, u16* __restrict__ dst,
                                long long wz, long long dz) {
  __shared__ float t[32][33];
  int n0 = blockIdx.x * 32, k0 = blockIdx.y * 32;
  int which = n0 / 768;
  int r0 = n0 % 768;
  int h = r0 >> 6, e0 = r0 & 63;
  const float* src = which == 0 ? wq : (which == 1 ? wk : wv);
  src += (size_t)blockIdx.z * wz;
  dst += (size_t)blockIdx.z * dz;
  int tid = threadIdx.x;
  int tx = tid & 31, ty = tid >> 5;
  for (int r = ty; r < 32; r += 8) t[r][tx] = src[(size_t)(h * 768 + k0 + r) * 64 + e0 + tx];
  __syncthreads();
  for (int r = ty; r < 32; r += 8) dst[(size_t)(n0 + r) * 768 + k0 + tx] = f2bf(t[tx][r]);
}

// ---------------------------------------------------------------------------
// gemm128 (round-6 proven loop, NO grid swizzle — r11): C[M,N] = A[M,K]*Wt[N,K],
// 128xBN tile, BK=64, 4 waves, 2-barrier loop, global_load_lds width-16,
// both-sides XOR swizzle, hoisted addresses, NK=6 unroll x kOuter chunks.
// MODE 0: Q/K scatter; V blocks (n0>=1536) write vt[bh][e][s] DIRECTLY from
//   registers (4 acc regs = 4 consecutive s at fixed (h,e) -> one u16x4 store
//   per fragment, 16 vs 64 stores/thread; no LDS, no extra barriers — unlike
//   r8's failed LDS-transpose version). Removes transpose_v entirely.
// MODE 1: xf += C  MODE 2: gelu(C+b1)->bf16  MODE 3: xf += C + b2 (+outf)
// ---------------------------------------------------------------------------
template <int MODE, int NK, int BN>
__global__ __launch_bounds__(256) void gemm128(
    const u16* __restrict__ A, int lda, const u16* __restrict__ Wt, int ldb, int kOuter,
    float* __restrict__ xf, u16* __restrict__ outb, const float* __restrict__ bias,
    u16* __restrict__ qb, u16* __restrict__ kb, u16* __restrict__ vtb,
    float* __restrict__ outf) {
  constexpr int NT = BN / 32;                 // B frags per wave (4 or 2)
  constexpr int NBAND = BN / 2;               // wave N width
  __shared__ alignas(16) u16 As[128 * 64];
  __shared__ alignas(16) u16 Bs[BN * 64];
  int tid = threadIdx.x, lane = tid & 63, w = tid >> 6;
  int wm = w >> 1, wn = w & 1;
  int m0 = blockIdx.x * 128, n0 = blockIdx.y * BN;
  f32x4 acc[4][NT] = {};
  int lr = lane >> 3;
  int cb = (lane & 7) << 4;
  int sws = cb ^ (lr << 4);
  const char* pA = (const char*)(A + (size_t)m0 * lda) + (size_t)(w * 8 + lr) * (lda * 2) + sws;
  const char* pB = (const char*)(Wt + (size_t)n0 * ldb) + (size_t)(w * 8 + lr) * (ldb * 2) + sws;
  char* dA = (char*)As + w * 1024;
  char* dB = (char*)Bs + w * 1024;
  int arow = wm * 64 + (lane & 15);
  int brow = wn * NBAND + (lane & 15);
  int e0 = (lane >> 4) * 8;
  for (int c = 0; c < kOuter; ++c) {
    #pragma unroll
    for (int kt = 0; kt < NK; ++kt) {
      __syncthreads();
      #pragma unroll
      for (int i = 0; i < 4; ++i)
        __builtin_amdgcn_global_load_lds((gvoid_t*)(pA + (size_t)i * 32 * (lda * 2)),
                                         (lvoid_t*)(dA + i * 4096), 16, 0, 0);
      #pragma unroll
      for (int i = 0; i < BN / 32; ++i)
        __builtin_amdgcn_global_load_lds((gvoid_t*)(pB + (size_t)i * 32 * (ldb * 2)),
                                         (lvoid_t*)(dB + i * 4096), 16, 0, 0);
      pA += 128; pB += 128;
      __syncthreads();   // compiler emits vmcnt(0) drain (staged data ready)
      #pragma unroll
      for (int kk = 0; kk < 2; ++kk) {
        bf16x8 af[4], bfr[NT];
        #pragma unroll
        for (int mt = 0; mt < 4; ++mt) af[mt] = ldsfrag(As, arow + mt * 16, kk * 32 + e0);
        #pragma unroll
        for (int nt = 0; nt < NT; ++nt) bfr[nt] = ldsfrag(Bs, brow + nt * 16, kk * 32 + e0);
        #pragma unroll
        for (int mt = 0; mt < 4; ++mt)
          #pragma unroll
          for (int nt = 0; nt < NT; ++nt)
            acc[mt][nt] = MFMA(af[mt], bfr[nt], acc[mt][nt]);
      }
    }
  }
  int rbase = m0 + wm * 64 + ((lane >> 4) << 2);
  int cbase = n0 + wn * NBAND + (lane & 15);
  if constexpr (MODE == 0) {
    int which = n0 / 768;
    if (which < 2) {
      u16* dstb = which == 0 ? qb : kb;
      int cloc = cbase - which * 768;
      #pragma unroll
      for (int mt = 0; mt < 4; ++mt) {
        #pragma unroll
        for (int nt = 0; nt < NT; ++nt) {
          int rr = cloc + nt * 16;
          int h = rr >> 6, e = rr & 63;
          #pragma unroll
          for (int reg = 0; reg < 4; ++reg) {
            int row = rbase + mt * 16 + reg;
            int b = row >> 10, s = row & 1023;
            dstb[((size_t)(b * 12 + h) * 1024 + s) * 64 + e] = f2bf(acc[mt][nt][reg]);
          }
        }
      }
    } else {
      // V: write transposed vt[bh][e][s] directly; the 4 acc regs of each
      // fragment are consecutive s at fixed (h,e) -> one u16x4 (8B) store.
      #pragma unroll
      for (int mt = 0; mt < 4; ++mt) {
        int row0 = rbase + mt * 16;          // 4 consecutive rows from here
        int b = row0 >> 10, s = row0 & 1023; // 128|1024: no b crossing
        #pragma unroll
        for (int nt = 0; nt < NT; ++nt) {
          int rr = cbase - 1536 + nt * 16;
          int h = rr >> 6, e = rr & 63;
          u16x4 ov;
          ov.x = f2bf(acc[mt][nt][0]);
          ov.y = f2bf(acc[mt][nt][1]);
          ov.z = f2bf(acc[mt][nt][2]);
          ov.w = f2bf(acc[mt][nt][3]);
          *(u16x4*)(vtb + ((size_t)((b * 12 + h) * 64 + e)) * 1024 + s) = ov;
        }
      }
    }
  } else if constexpr (MODE == 2) {
    #pragma unroll
    for (int mt = 0; mt < 4; ++mt) {
      #pragma unroll
      for (int nt = 0; nt < NT; ++nt) {
        int col = cbase + nt * 16;
        float bb = bias[col];
        #pragma unroll
        for (int reg = 0; reg < 4; ++reg) {
          int row = rbase + mt * 16 + reg;
          float t = acc[mt][nt][reg] + bb;
          float u = t * fmaf(t * t, 0.044715f, 1.0f);
          float ex = __builtin_amdgcn_exp2f(u * -2.3022156f);
          float g = t * __builtin_amdgcn_rcpf(1.0f + ex);
          outb[(size_t)row * 3072 + col] = f2bf(g);
        }
      }
    }
  } else {
    #pragma unroll
    for (int mt = 0; mt < 4; ++mt) {
      #pragma unroll
      for (int nt = 0; nt < NT; ++nt) {
        int col = cbase + nt * 16;
        float bb = (MODE == 3) ? bias[col] : 0.0f;
        #pragma unroll
        for (int reg = 0; reg < 4; ++reg) {
          int row = rbase + mt * 16 + reg;
          size_t idx = (size_t)row * 768 + col;
          float nv = xf[idx] + acc[mt][nt][reg] + bb;
          xf[idx] = nv;
          if (MODE == 3 && outf) outf[idx] = nv;
        }
      }
    }
  }
}

// ---------------------------------------------------------------------------
// flash128: Q-block 128 (two 64-row halves share staged K/V AND the K-frag
// ds_reads). Fixed-shift softmax (exact), l = P@ones via MFMA, double-
// buffered K/V, P-tile LDS reused across halves. No grid swizzle (r11).
// q,k: [bh][s][64] ; vt: [bh][e][s] ; o: [b,s, head*64+e]
// ---------------------------------------------------------------------------
__global__ __launch_bounds__(256) void flash128(
    const u16* __restrict__ q, const u16* __restrict__ k, const u16* __restrict__ vt,
    const int* __restrict__ kmask, u16* __restrict__ o) {
  __shared__ alignas(16) u16 Ks[2][64 * 64];
  __shared__ alignas(16) u16 Vs[2][64 * 64];
  __shared__ alignas(16) u16 Ps[64 * 64];
  int tid = threadIdx.x, lane = tid & 63, w = tid >> 6;
  int lc = lane & 15;
  int bh = blockIdx.x, q0 = blockIdx.y * 128;
  int b = bh / 12, hd = bh % 12;

  stage64(q + ((size_t)bh * 1024 + q0) * 64, 64, Ps, 64, tid);
  stage64(q + ((size_t)bh * 1024 + q0 + 64) * 64, 64, Ks[0], 64, tid);
  __syncthreads();
  int qrow = w * 16 + lc;
  int e0 = (lane >> 4) * 8;
  bf16x8 aq[2][2];
  aq[0][0] = ldsfrag(Ps, qrow, e0);
  aq[0][1] = ldsfrag(Ps, qrow, 32 + e0);
  aq[1][0] = ldsfrag(Ks[0], qrow, e0);
  aq[1][1] = ldsfrag(Ks[0], qrow, 32 + e0);
  __syncthreads();   // all Q reads done before Ks[0] is overwritten

  bf16x8 ones;
  #pragma unroll
  for (int j = 0; j < 8; ++j) ones[j] = (__bf16)1.0f;

  f32x4 oacc[2][4] = {};
  f32x4 lacc[2] = {};
  const float SCL = 0.125f * 1.44269504f;
  const float SH = -3.0f * 1.44269504f;
  int prow_base = w * 16 + ((lane >> 4) << 2);

  stage64(k + (size_t)bh * 1024 * 64, 64, Ks[0], 64, tid);
  stage64(vt + (size_t)bh * 64 * 1024, 1024, Vs[0], 64, tid);

  for (int kt = 0; kt < 16; ++kt) {
    asm volatile("s_waitcnt vmcnt(0)" ::: "memory");
    __builtin_amdgcn_sched_barrier(0);
    __builtin_amdgcn_s_barrier();
    __builtin_amdgcn_sched_barrier(0);
    const u16* Kc = Ks[kt & 1];
    const u16* Vc = Vs[kt & 1];

    f32x4 sacc[2][4] = {};
    #pragma unroll
    for (int nt = 0; nt < 4; ++nt) {
      bf16x8 bk0 = ldsfrag(Kc, nt * 16 + lc, e0);
      bf16x8 bk1 = ldsfrag(Kc, nt * 16 + lc, 32 + e0);
      sacc[0][nt] = MFMA(aq[0][0], bk0, sacc[0][nt]);
      sacc[0][nt] = MFMA(aq[0][1], bk1, sacc[0][nt]);
      sacc[1][nt] = MFMA(aq[1][0], bk0, sacc[1][nt]);
      sacc[1][nt] = MFMA(aq[1][1], bk1, sacc[1][nt]);
    }

    if (kt + 1 < 16) {
      stage64(k + ((size_t)bh * 1024 + (kt + 1) * 64) * 64, 64, Ks[(kt + 1) & 1], 64, tid);
      stage64(vt + (size_t)bh * 64 * 1024 + (kt + 1) * 64, 1024, Vs[(kt + 1) & 1], 64, tid);
    }

    float mkv[4];
    #pragma unroll
    for (int nt = 0; nt < 4; ++nt)
      mkv[nt] = kmask[b * 1024 + kt * 64 + nt * 16 + lc] ? SH : -1e30f;

    #pragma unroll
    for (int h = 0; h < 2; ++h) {
      #pragma unroll
      for (int nt = 0; nt < 4; ++nt) {
        int c = nt * 16 + lc;
        #pragma unroll
        for (int r = 0; r < 4; ++r) {
          float p = __builtin_amdgcn_exp2f(fmaf(sacc[h][nt][r], SCL, mkv[nt]));
          int prow = prow_base + r;
          int boff = prow * 128 + ((c << 1) ^ ((prow & 7) << 4));
          *(u16*)((char*)Ps + boff) = f2bf(p);
        }
      }
      bf16x8 ap0 = ldsfrag(Ps, qrow, e0);
      bf16x8 ap1 = ldsfrag(Ps, qrow, 32 + e0);
      lacc[h] = MFMA(ap0, ones, lacc[h]);
      lacc[h] = MFMA(ap1, ones, lacc[h]);
      #pragma unroll
      for (int et = 0; et < 4; ++et) {
        bf16x8 bv = ldsfrag(Vc, et * 16 + lc, e0);
        oacc[h][et] = MFMA(ap0, bv, oacc[h][et]);
      }
      #pragma unroll
      for (int et = 0; et < 4; ++et) {
        bf16x8 bv = ldsfrag(Vc, et * 16 + lc, 32 + e0);
        oacc[h][et] = MFMA(ap1, bv, oacc[h][et]);
      }
    }
  }

  #pragma unroll
  for (int h = 0; h < 2; ++h) {
    float rl[4];
    #pragma unroll
    for (int r = 0; r < 4; ++r) rl[r] = __builtin_amdgcn_rcpf(lacc[h][r]);
    int orow_base = q0 + h * 64 + prow_base;
    #pragma unroll
    for (int et = 0; et < 4; ++et) {
      int e = et * 16 + lc;
      #pragma unroll
      for (int r = 0; r < 4; ++r) {
        int row = orow_base + r;
        o[((size_t)(b * 1024 + row)) * 768 + hd * 64 + e] = f2bf(oacc[h][et][r] * rl[r]);
      }
    }
  }
}

// ---------------------------------------------------------------------------
extern "C" void kernel_launch(void* const* d_in, const int* in_sizes, int n_in,
                              void* d_out, int out_size, void* d_ws, size_t ws_size,
                              hipStream_t stream) {
  const int* tokens = (const int*)d_in[0];
  const int* kmask = (const int*)d_in[1];
  const float* emb = (const float*)d_in[2];
  const float* pe = (const float*)d_in[3];
  const float* ln1_s = (const float*)d_in[4];
  const float* ln1_b = (const float*)d_in[5];
  const float* wq = (const float*)d_in[6];
  const float* wk = (const float*)d_in[7];
  const float* wv = (const float*)d_in[8];
  const float* wo = (const float*)d_in[9];
  const float* ln2_s = (const float*)d_in[10];
  const float* ln2_b = (const float*)d_in[11];
  const float* w1 = (const float*)d_in[12];
  const float* b1 = (const float*)d_in[13];
  const float* w2 = (const float*)d_in[14];
  const float* b2 = (const float*)d_in[15];

  char* ws = (char*)d_ws;
  float* xf = (float*)ws;                       // 8192*768*4
  u16* xn   = (u16*)(ws + 25165824);
  u16* qb   = (u16*)(ws + 37748736);
  u16* kb   = (u16*)(ws + 50331648);
  u16* vtb  = (u16*)(ws + 75497472);
  u16* ob   = (u16*)(ws + 88080384);
  u16* ffh  = (u16*)(ws + 100663296);           // 8192*3072*2

  const size_t SZ_QKV = (size_t)2304 * 768;
  const size_t SZ_O   = (size_t)768 * 768;
  const size_t SZ_F1  = (size_t)3072 * 768;
  const size_t SZ_F2  = (size_t)768 * 3072;
  const size_t NEED = 150994944 + 2 * 6 * (SZ_QKV + SZ_O + SZ_F1 + SZ_F2);
  bool pre = ws_size >= NEED;
  int nz = pre ? 6 : 1;
  u16* wqkvt = (u16*)(ws + 150994944);
  u16* wot   = wqkvt + (size_t)nz * SZ_QKV;
  u16* w1t   = wot + (size_t)nz * SZ_O;
  u16* w2t   = w1t + (size_t)nz * SZ_F1;

  embed_kernel<<<8192, 192, 0, stream>>>(tokens, emb, pe, xf);

  if (pre) {
    convqkvT_kernel<<<dim3(72, 24, 6), 256, 0, stream>>>(wq, wk, wv, wqkvt, 589824LL, (long long)SZ_QKV);
    convT_kernel<<<dim3(24, 24, 6), 256, 0, stream>>>(wo, wot, 768, 768, 589824LL, (long long)SZ_O);
    convT_kernel<<<dim3(96, 24, 6), 256, 0, stream>>>(w1, w1t, 3072, 768, 2359296LL, (long long)SZ_F1);
    convT_kernel<<<dim3(24, 96, 6), 256, 0, stream>>>(w2, w2t, 768, 3072, 2359296LL, (long long)SZ_F2);
  }

  for (int l = 0; l < 6; ++l) {
    size_t woff_qkv = (size_t)l * 12 * 768 * 64;
    size_t woff_o = (size_t)l * 768 * 768;
    size_t woff_ff = (size_t)l * 768 * 3072;
    const u16* wt_qkv_l = wqkvt + (pre ? (size_t)l * SZ_QKV : 0);
    const u16* wt_o_l   = wot   + (pre ? (size_t)l * SZ_O   : 0);
    const u16* wt_1_l   = w1t   + (pre ? (size_t)l * SZ_F1  : 0);
    const u16* wt_2_l   = w2t   + (pre ? (size_t)l * SZ_F2  : 0);

    if (!pre) {
      convqkvT_kernel<<<dim3(72, 24, 1), 256, 0, stream>>>(wq + woff_qkv, wk + woff_qkv, wv + woff_qkv, (u16*)wt_qkv_l, 0LL, 0LL);
      convT_kernel<<<dim3(24, 24, 1), 256, 0, stream>>>(wo + woff_o, (u16*)wt_o_l, 768, 768, 0LL, 0LL);
      convT_kernel<<<dim3(96, 24, 1), 256, 0, stream>>>(w1 + woff_ff, (u16*)wt_1_l, 3072, 768, 0LL, 0LL);
      convT_kernel<<<dim3(24, 96, 1), 256, 0, stream>>>(w2 + woff_ff, (u16*)wt_2_l, 768, 3072, 0LL, 0LL);
    }

    ln_kernel<<<2048, 256, 0, stream>>>(xf, ln1_s + l * 768, ln1_b + l * 768, xn);
    gemm128<0, 6, 128><<<dim3(64, 18, 1), 256, 0, stream>>>(xn, 768, wt_qkv_l, 768, 2, nullptr, nullptr, nullptr, qb, kb, vtb, nullptr);
    flash128<<<dim3(96, 8), 256, 0, stream>>>(qb, kb, vtb, kmask, ob);
    gemm128<1, 6, 64><<<dim3(64, 12, 1), 256, 0, stream>>>(ob, 768, wt_o_l, 768, 2, xf, nullptr, nullptr, nullptr, nullptr, nullptr, nullptr);
    ln_kernel<<<2048, 256, 0, stream>>>(xf, ln2_s + l * 768, ln2_b + l * 768, xn);
    gemm128<2, 6, 128><<<dim3(64, 24, 1), 256, 0, stream>>>(xn, 768, wt_1_l, 768, 2, nullptr, ffh, b1 + l * 3072, nullptr, nullptr, nullptr, nullptr);
    gemm128<3, 6, 64><<<dim3(64, 12, 1), 256, 0, stream>>>(ffh, 3072, wt_2_l, 3072, 8, xf, nullptr, b2 + l * 768, nullptr, nullptr, nullptr,
                                                           (l == 5) ? (float*)d_out : nullptr);
  }
}